// Round 2
// baseline (177.510 us; speedup 1.0000x reference)
//
#include <hip/hip_runtime.h>
#include <hip/hip_bf16.h>
#include <stdint.h>

#define KNN 8
#define S_ 5
#define D_ 5
#define NDE 4
#define NDC 12
#define NDD 16
#define NPOS 80
#define ACT 5
#define PERK 172
#define XROW 1376
#define FEAT 784
#define FEATP 800
#define H1 512

typedef __bf16 bf16x8 __attribute__((ext_vector_type(8)));
typedef float f32x4 __attribute__((ext_vector_type(4)));

static __device__ __forceinline__ unsigned short f2bf(float f) {
    unsigned int u = __builtin_bit_cast(unsigned int, f);
    u += 0x7fff + ((u >> 16) & 1);   // round-to-nearest-even
    return (unsigned short)(u >> 16);
}
static __device__ __forceinline__ float fsgnsqrt(float t) {
    return copysignf(sqrtf(fabsf(t)), t);
}

// ---------------- K0: W1 -> bf16, K-padded 784->800 ----------------
__global__ __launch_bounds__(256) void k_prep(const float* __restrict__ W1,
                                              unsigned short* __restrict__ w1bf)
{
    int idx = blockIdx.x * 256 + threadIdx.x;
    if (idx >= H1 * FEATP) return;
    int n = idx / FEATP, k = idx - n * FEATP;
    float v = (k < FEAT) ? W1[n * FEAT + k] : 0.f;
    w1bf[idx] = f2bf(v);
}

// ---------------- Kw: noisy-net effective weights (6 x 512) + biases ----------------
__global__ __launch_bounds__(512) void k_noisy(const float* __restrict__ adv_uw,
                                               const float* __restrict__ adv_sw,
                                               const float* __restrict__ adv_ub,
                                               const float* __restrict__ adv_sb,
                                               const float* __restrict__ v_uw,
                                               const float* __restrict__ v_sw,
                                               const float* __restrict__ v_ub,
                                               const float* __restrict__ v_sb,
                                               const float* __restrict__ ei_a,
                                               const float* __restrict__ eo_a,
                                               const float* __restrict__ ei_v,
                                               const float* __restrict__ eo_v,
                                               float* __restrict__ wv,
                                               float* __restrict__ bias)
{
    int n = threadIdx.x;   // 0..511
    float fia = fsgnsqrt(ei_a[n]);
    float fiv = fsgnsqrt(ei_v[n]);
    #pragma unroll
    for (int a = 0; a < ACT; a++) {
        float fo = fsgnsqrt(eo_a[a]);
        wv[a * H1 + n] = adv_uw[a * H1 + n] + adv_sw[a * H1 + n] * fo * fia;
    }
    float fov = fsgnsqrt(eo_v[0]);
    wv[5 * H1 + n] = v_uw[n] + v_sw[n] * fov * fiv;
    if (n < ACT) bias[n] = adv_ub[n] + adv_sb[n] * fsgnsqrt(eo_a[n]);
    if (n == 5) bias[5] = v_ub[0] + v_sb[0] * fov;
}

// ---------------- K1: GNN + gather -> feat (bf16, padded to 800) ----------------
__global__ __launch_bounds__(128) void k_feat(const float* __restrict__ x,
                                              const float* __restrict__ Wg,
                                              const float* __restrict__ bg,
                                              unsigned short* __restrict__ featbf)
{
    __shared__ float xrow[XROW];
    __shared__ float sWg[NDC * NDC];
    __shared__ float sbg[NDC];
    __shared__ int   snd[NPOS];
    __shared__ int   sfirst[NPOS];
    __shared__ int   smfirst[NPOS];
    __shared__ float scnt[NPOS];
    __shared__ float sdis[NPOS];
    __shared__ float sM[NPOS * NDC];
    __shared__ float sH[NPOS * NDC];

    const int b = blockIdx.x;
    const int tid = threadIdx.x;
    const float* xp = x + (size_t)b * XROW;
    for (int i = tid; i < XROW; i += 128) xrow[i] = xp[i];
    for (int i = tid; i < NDC * NDC; i += 128) sWg[i] = Wg[i];   // FIX: 144 > blockDim, must stride
    if (tid < NDC) sbg[tid] = bg[tid];
    __syncthreads();

    if (tid < NPOS) {
        int k = tid / 10, m = tid % 10;
        snd[tid] = (int)xrow[k * PERK + 160 + m];
    }
    __syncthreads();

    if (tid < NPOS) {
        int i = tid;
        int ndi = snd[i];
        int f = 0;
        while (snd[f] != ndi) f++;                 // global first occurrence
        int kbase = (i / 10) * 10;
        int mf = kbase;
        while (snd[mf] != ndi) mf++;               // within-knn first occurrence
        int r = ndi >> 5, c = ndi & 31;
        int nb0 = (((r + 31) & 31) << 5) | c;
        int nb1 = (((r + 1) & 31) << 5) | c;
        int nb2 = (r << 5) | ((c + 31) & 31);
        int nb3 = (r << 5) | ((c + 1) & 31);
        int cnt = 0, adjd = 0;
        for (int j = 0; j < NPOS; j++) {
            int nj = snd[j];
            cnt += (nj == ndi);
            adjd += ((nj == nb0) | (nj == nb1) | (nj == nb2) | (nj == nb3));
        }
        sfirst[i] = f;
        smfirst[i] = mf;
        scnt[i] = (float)cnt;
        float deg = 1.0f + ((f == i) ? (float)adjd : 0.0f);
        sdis[i] = 1.0f / sqrtf(deg);
    }
    // M = all_info @ Wg, row per thread
    if (tid < NPOS) {
        int i = tid;
        int k = i / 10, m = i % 10;
        int off = k * PERK + m * NDD;   // start/dest blocks are contiguous: both reduce to m*16
        float ai[NDC];
        #pragma unroll
        for (int c2 = 0; c2 < NDC; c2++) ai[c2] = xrow[off + NDE + c2];
        #pragma unroll
        for (int d = 0; d < NDC; d++) {
            float s = 0.f;
            #pragma unroll
            for (int c2 = 0; c2 < NDC; c2++) s += ai[c2] * sWg[c2 * NDC + d];
            sM[i * NDC + d] = s;
        }
    }
    __syncthreads();

    // H[t] = relu( dis_t * is_first[t] * sum_{s first} cnt_s*ADJ*dis_s*M[s] + dis_t^2*M[t] + bg )
    if (tid < NPOS) {
        int t = tid;
        float dt = sdis[t];
        float acc[NDC];
        float d2 = dt * dt;
        #pragma unroll
        for (int d = 0; d < NDC; d++) acc[d] = d2 * sM[t * NDC + d];
        if (sfirst[t] == t) {
            int ndt = snd[t];
            int r = ndt >> 5, c = ndt & 31;
            int nb0 = (((r + 31) & 31) << 5) | c;
            int nb1 = (((r + 1) & 31) << 5) | c;
            int nb2 = (r << 5) | ((c + 31) & 31);
            int nb3 = (r << 5) | ((c + 1) & 31);
            for (int s = 0; s < NPOS; s++) {
                if (sfirst[s] != s) continue;
                int ns = snd[s];
                if ((ns == nb0) | (ns == nb1) | (ns == nb2) | (ns == nb3)) {
                    float w = scnt[s] * sdis[s] * dt;
                    #pragma unroll
                    for (int d = 0; d < NDC; d++) acc[d] += w * sM[s * NDC + d];
                }
            }
        }
        #pragma unroll
        for (int d = 0; d < NDC; d++) sH[t * NDC + d] = fmaxf(acc[d] + sbg[d], 0.f);
    }
    __syncthreads();

    // gather into feat layout: per k: [6x12 gnn][2 els][6x4 each], pad 784->800 with zeros
    unsigned short* fout = featbf + (size_t)b * FEATP;
    for (int idx = tid; idx < FEATP; idx += 128) {
        float val = 0.f;
        if (idx < FEAT) {
            int k = idx / 98, rr = idx % 98;
            if (rr < 72) {
                int t = rr / 12, d = rr % 12;
                val = sH[sfirst[k * 10 + t] * NDC + d];
            } else if (rr < 74) {
                val = xrow[k * PERK + 170 + (rr - 72)];
            } else {
                int q = rr - 74;
                int t = q >> 2, e = q & 3;
                int m = smfirst[k * 10 + t] - k * 10;
                val = xrow[k * PERK + m * NDD + e];
            }
        }
        fout[idx] = f2bf(val);
    }
}

// ---------------- K2: h = relu(feat @ W1^T + b1), bf16 MFMA ----------------
__global__ __launch_bounds__(256) void k_gemm(const unsigned short* __restrict__ A,
                                              const unsigned short* __restrict__ Bw,
                                              const float* __restrict__ b1,
                                              float* __restrict__ h, int nB)
{
    int tid = threadIdx.x;
    int lane = tid & 63;
    int w = tid >> 6;
    int nbm = nB >> 6;
    int bm = (blockIdx.x % nbm) * 64;
    int bn = (blockIdx.x / nbm) * 64;
    int wr = w >> 1, wc = w & 1;
    int l15 = lane & 15;
    int kb = (lane >> 4) * 8;

    const unsigned short* pa0 = A + (size_t)(bm + wr * 32 + l15) * FEATP + kb;
    const unsigned short* pa1 = pa0 + 16 * FEATP;
    const unsigned short* pb0 = Bw + (size_t)(bn + wc * 32 + l15) * FEATP + kb;
    const unsigned short* pb1 = pb0 + 16 * FEATP;

    f32x4 c00 = {0, 0, 0, 0}, c01 = {0, 0, 0, 0}, c10 = {0, 0, 0, 0}, c11 = {0, 0, 0, 0};
    #pragma unroll 5
    for (int kk = 0; kk < FEATP / 32; kk++) {
        bf16x8 a0  = __builtin_bit_cast(bf16x8, *(const uint4*)(pa0 + kk * 32));
        bf16x8 a1  = __builtin_bit_cast(bf16x8, *(const uint4*)(pa1 + kk * 32));
        bf16x8 bb0 = __builtin_bit_cast(bf16x8, *(const uint4*)(pb0 + kk * 32));
        bf16x8 bb1 = __builtin_bit_cast(bf16x8, *(const uint4*)(pb1 + kk * 32));
        c00 = __builtin_amdgcn_mfma_f32_16x16x32_bf16(a0, bb0, c00, 0, 0, 0);
        c01 = __builtin_amdgcn_mfma_f32_16x16x32_bf16(a0, bb1, c01, 0, 0, 0);
        c10 = __builtin_amdgcn_mfma_f32_16x16x32_bf16(a1, bb0, c10, 0, 0, 0);
        c11 = __builtin_amdgcn_mfma_f32_16x16x32_bf16(a1, bb1, c11, 0, 0, 0);
    }
    // C/D layout: col = lane&15, row = (lane>>4)*4 + reg   [learn_hip m89]
    int row0 = bm + wr * 32 + (lane >> 4) * 4;
    int col0 = bn + wc * 32 + l15;
    float bias0 = b1[col0];
    float bias1 = b1[col0 + 16];
    #pragma unroll
    for (int r = 0; r < 4; r++) {
        h[(size_t)(row0 + r) * H1 + col0]           = fmaxf(c00[r] + bias0, 0.f);
        h[(size_t)(row0 + r) * H1 + col0 + 16]      = fmaxf(c01[r] + bias1, 0.f);
        h[(size_t)(row0 + 16 + r) * H1 + col0]      = fmaxf(c10[r] + bias0, 0.f);
        h[(size_t)(row0 + 16 + r) * H1 + col0 + 16] = fmaxf(c11[r] + bias1, 0.f);
    }
}

// ---------------- K3: dueling head, one wave per batch row ----------------
__global__ __launch_bounds__(256) void k_out(const float* __restrict__ h,
                                             const float* __restrict__ wv,
                                             const float* __restrict__ bias,
                                             float* __restrict__ out, int nB)
{
    int wave = blockIdx.x * 4 + (threadIdx.x >> 6);
    int lane = threadIdx.x & 63;
    if (wave >= nB) return;
    const float* hb = h + (size_t)wave * H1;
    int base = lane * 8;
    float hv[8];
    #pragma unroll
    for (int j = 0; j < 8; j++) hv[j] = hb[base + j];
    float acc[6];
    #pragma unroll
    for (int a = 0; a < 6; a++) {
        const float* wp = wv + a * H1 + base;
        float s = 0.f;
        #pragma unroll
        for (int j = 0; j < 8; j++) s += hv[j] * wp[j];
        acc[a] = s;
    }
    #pragma unroll
    for (int a = 0; a < 6; a++) {
        #pragma unroll
        for (int off = 32; off > 0; off >>= 1) acc[a] += __shfl_xor(acc[a], off, 64);
    }
    float adv[5], ssum = 0.f;
    #pragma unroll
    for (int a = 0; a < 5; a++) { adv[a] = acc[a] + bias[a]; ssum += adv[a]; }
    float vv = acc[5] + bias[5];
    if (lane < 5) out[(size_t)wave * 5 + lane] = vv + adv[lane] - ssum * 0.2f;
}

extern "C" void kernel_launch(void* const* d_in, const int* in_sizes, int n_in,
                              void* d_out, int out_size, void* d_ws, size_t ws_size,
                              hipStream_t stream)
{
    const float* x      = (const float*)d_in[0];
    const float* Wg     = (const float*)d_in[1];
    const float* bg     = (const float*)d_in[2];
    const float* W1     = (const float*)d_in[3];
    const float* b1     = (const float*)d_in[4];
    const float* adv_uw = (const float*)d_in[5];
    const float* adv_sw = (const float*)d_in[6];
    const float* adv_ub = (const float*)d_in[7];
    const float* adv_sb = (const float*)d_in[8];
    const float* v_uw   = (const float*)d_in[9];
    const float* v_sw   = (const float*)d_in[10];
    const float* v_ub   = (const float*)d_in[11];
    const float* v_sb   = (const float*)d_in[12];
    const float* ei_a   = (const float*)d_in[13];
    const float* eo_a   = (const float*)d_in[14];
    const float* ei_v   = (const float*)d_in[15];
    const float* eo_v   = (const float*)d_in[16];

    int nB = in_sizes[0] / XROW;   // 4096

    char* ws = (char*)d_ws;
    unsigned short* w1bf   = (unsigned short*)ws;                         // 512*800*2
    unsigned short* featbf = (unsigned short*)(ws + 819200);              // nB*800*2
    float* h    = (float*)(ws + 819200 + (size_t)nB * FEATP * 2);         // nB*512*4
    float* wv   = (float*)((char*)h + (size_t)nB * H1 * 4);               // 6*512*4
    float* bias = wv + 6 * H1;                                            // 6*4
    float* out  = (float*)d_out;

    hipLaunchKernelGGL(k_prep, dim3((H1 * FEATP + 255) / 256), dim3(256), 0, stream, W1, w1bf);
    hipLaunchKernelGGL(k_noisy, dim3(1), dim3(512), 0, stream,
                       adv_uw, adv_sw, adv_ub, adv_sb, v_uw, v_sw, v_ub, v_sb,
                       ei_a, eo_a, ei_v, eo_v, wv, bias);
    hipLaunchKernelGGL(k_feat, dim3(nB), dim3(128), 0, stream, x, Wg, bg, featbf);
    hipLaunchKernelGGL(k_gemm, dim3((nB / 64) * (H1 / 64)), dim3(256), 0, stream,
                       featbf, w1bf, b1, h, nB);
    hipLaunchKernelGGL(k_out, dim3((nB + 3) / 4), dim3(256), 0, stream, h, wv, bias, out, nB);
}

// Round 3
// 148.572 us; speedup vs baseline: 1.1948x; 1.1948x over previous
//
#include <hip/hip_runtime.h>
#include <hip/hip_bf16.h>
#include <stdint.h>

#define KNN 8
#define S_ 5
#define D_ 5
#define NDE 4
#define NDC 12
#define NDD 16
#define NPOS 80
#define ACT 5
#define PERK 172
#define XROW 1376
#define FEAT 784
#define FEATP 800
#define H1 512

typedef __bf16 bf16x8 __attribute__((ext_vector_type(8)));
typedef float f32x4 __attribute__((ext_vector_type(4)));

static __device__ __forceinline__ unsigned short f2bf(float f) {
    unsigned int u = __builtin_bit_cast(unsigned int, f);
    u += 0x7fff + ((u >> 16) & 1);   // round-to-nearest-even
    return (unsigned short)(u >> 16);
}
static __device__ __forceinline__ float fsgnsqrt(float t) {
    return copysignf(sqrtf(fabsf(t)), t);
}

// ---------------- K0: W1 -> bf16 (K-pad 784->800)  +  noisy weights (last block) ----------------
__global__ __launch_bounds__(256) void k_prep(const float* __restrict__ W1,
                                              unsigned short* __restrict__ w1bf,
                                              const float* __restrict__ adv_uw,
                                              const float* __restrict__ adv_sw,
                                              const float* __restrict__ adv_ub,
                                              const float* __restrict__ adv_sb,
                                              const float* __restrict__ v_uw,
                                              const float* __restrict__ v_sw,
                                              const float* __restrict__ v_ub,
                                              const float* __restrict__ v_sb,
                                              const float* __restrict__ ei_a,
                                              const float* __restrict__ eo_a,
                                              const float* __restrict__ ei_v,
                                              const float* __restrict__ eo_v,
                                              float* __restrict__ wv,
                                              float* __restrict__ bias,
                                              int nblk)
{
    if ((int)blockIdx.x == nblk - 1) {
        int tid = threadIdx.x;
        for (int n = tid; n < H1; n += 256) {
            float fia = fsgnsqrt(ei_a[n]);
            float fiv = fsgnsqrt(ei_v[n]);
            #pragma unroll
            for (int a = 0; a < ACT; a++)
                wv[a * H1 + n] = adv_uw[a * H1 + n] + adv_sw[a * H1 + n] * fsgnsqrt(eo_a[a]) * fia;
            wv[5 * H1 + n] = v_uw[n] + v_sw[n] * fsgnsqrt(eo_v[0]) * fiv;
        }
        if (tid < ACT) bias[tid] = adv_ub[tid] + adv_sb[tid] * fsgnsqrt(eo_a[tid]);
        if (tid == ACT) bias[5] = v_ub[0] + v_sb[0] * fsgnsqrt(eo_v[0]);
        return;
    }
    int idx = blockIdx.x * 256 + threadIdx.x;
    if (idx >= H1 * FEATP) return;
    int n = idx / FEATP, k = idx - n * FEATP;
    float v = (k < FEAT) ? W1[n * FEAT + k] : 0.f;
    w1bf[idx] = f2bf(v);
}

// ---------------- K1: GNN + gather -> feat (bf16, padded to 800) ----------------
__global__ __launch_bounds__(128) void k_feat(const float* __restrict__ x,
                                              const float* __restrict__ Wg,
                                              const float* __restrict__ bg,
                                              unsigned short* __restrict__ featbf)
{
    __shared__ float xrow[XROW];
    __shared__ float sWg[NDC * NDC];
    __shared__ float sbg[NDC];
    __shared__ int   snd[NPOS];
    __shared__ int   sfirst[NPOS];
    __shared__ int   smfirst[NPOS];
    __shared__ float scw[NPOS];          // cnt * dis  (only needed product)
    __shared__ float sdis[NPOS];
    __shared__ float sM[NPOS * NDC];
    __shared__ float sH[NPOS * NDC];

    const int b = blockIdx.x;
    const int tid = threadIdx.x;
    const float4* xp4 = (const float4*)(x + (size_t)b * XROW);
    float4* xr4 = (float4*)xrow;
    #pragma unroll
    for (int i = tid; i < XROW / 4; i += 128) xr4[i] = xp4[i];
    for (int i = tid; i < NDC * NDC; i += 128) sWg[i] = Wg[i];
    if (tid < NDC) sbg[tid] = bg[tid];
    __syncthreads();

    if (tid < NPOS) {
        int k = tid / 10, m = tid % 10;
        snd[tid] = (int)xrow[k * PERK + 160 + m];
    }
    __syncthreads();

    int s0 = 127, s1 = 127, s2 = 127, s3 = 127;   // first-occurrence idx of each neighbor value
    if (tid < NPOS) {
        const int i = tid;
        const int ndi = snd[i];
        const int kbase = (i / 10) * 10;
        int r = ndi >> 5, c = ndi & 31;
        int nb0 = (((r + 31) & 31) << 5) | c;
        int nb1 = (((r + 1) & 31) << 5) | c;
        int nb2 = (r << 5) | ((c + 31) & 31);
        int nb3 = (r << 5) | ((c + 1) & 31);
        int f = 127, mf = 127, cnt = 0, adjd = 0;
        #pragma unroll 8
        for (int j = 0; j < NPOS; j++) {
            int nj = snd[j];                      // broadcast read
            bool eq = (nj == ndi);
            cnt += eq;
            f  = min(f,  eq ? j : 127);
            mf = min(mf, (eq && j >= kbase) ? j : 127);
            adjd += (nj == nb0) + (nj == nb1) + (nj == nb2) + (nj == nb3);
            s0 = min(s0, (nj == nb0) ? j : 127);
            s1 = min(s1, (nj == nb1) ? j : 127);
            s2 = min(s2, (nj == nb2) ? j : 127);
            s3 = min(s3, (nj == nb3) ? j : 127);
        }
        sfirst[i] = f;
        smfirst[i] = mf;
        float dis = rsqrtf(1.0f + ((f == i) ? (float)adjd : 0.0f));
        sdis[i] = dis;
        scw[i] = (float)cnt * dis;
        // M = all_info @ Wg, one row per thread
        int off = (i / 10) * PERK + (i % 10) * NDD;
        float ai[NDC];
        #pragma unroll
        for (int c2 = 0; c2 < NDC; c2++) ai[c2] = xrow[off + NDE + c2];
        #pragma unroll
        for (int d = 0; d < NDC; d++) {
            float s = 0.f;
            #pragma unroll
            for (int c2 = 0; c2 < NDC; c2++) s += ai[c2] * sWg[c2 * NDC + d];
            sM[i * NDC + d] = s;
        }
    }
    __syncthreads();

    // H[t] = relu( d_t^2*M[t] + is_first[t]*d_t*sum_{X in 4 nbrs, sX exists} cnt_sX*d_sX*M[sX] + bg )
    if (tid < NPOS) {
        const int t = tid;
        float dt = sdis[t];
        float d2 = dt * dt;
        float acc[NDC];
        #pragma unroll
        for (int d = 0; d < NDC; d++) acc[d] = d2 * sM[t * NDC + d];
        if (sfirst[t] == t) {
            #pragma unroll
            for (int X = 0; X < 4; X++) {
                int sX = (X == 0) ? s0 : (X == 1) ? s1 : (X == 2) ? s2 : s3;
                if (sX < NPOS) {
                    float w = scw[sX] * dt;
                    #pragma unroll
                    for (int d = 0; d < NDC; d++) acc[d] += w * sM[sX * NDC + d];
                }
            }
        }
        #pragma unroll
        for (int d = 0; d < NDC; d++) sH[t * NDC + d] = fmaxf(acc[d] + sbg[d], 0.f);
    }
    __syncthreads();

    // gather into feat layout: per k: [6x12 gnn][2 els][6x4 each], pad 784->800 with zeros
    unsigned short* fout = featbf + (size_t)b * FEATP;
    for (int idx = tid; idx < FEATP; idx += 128) {
        float val = 0.f;
        if (idx < FEAT) {
            int k = idx / 98, rr = idx % 98;
            if (rr < 72) {
                int t = rr / 12, d = rr % 12;
                val = sH[sfirst[k * 10 + t] * NDC + d];
            } else if (rr < 74) {
                val = xrow[k * PERK + 170 + (rr - 72)];
            } else {
                int q = rr - 74;
                int t = q >> 2, e = q & 3;
                int m = smfirst[k * 10 + t] - k * 10;
                val = xrow[k * PERK + m * NDD + e];
            }
        }
        fout[idx] = f2bf(val);
    }
}

// ---------------- K2: h = relu(feat @ W1^T + b1), bf16 MFMA ----------------
__global__ __launch_bounds__(256) void k_gemm(const unsigned short* __restrict__ A,
                                              const unsigned short* __restrict__ Bw,
                                              const float* __restrict__ b1,
                                              float* __restrict__ h, int nB)
{
    int tid = threadIdx.x;
    int lane = tid & 63;
    int w = tid >> 6;
    // bijective XCD chunking: nwg = (nB/64)*8, divisible by 8
    int nwg = (nB >> 6) * 8;
    int cpx = nwg >> 3;
    int orig = blockIdx.x;
    int wg = (orig & 7) * cpx + (orig >> 3);
    int bn = (wg & 7) * 64;            // bn-major: 8 consecutive wg share one A-tile
    int bm = (wg >> 3) * 64;
    int wr = w >> 1, wc = w & 1;
    int l15 = lane & 15;
    int kb = (lane >> 4) * 8;

    const unsigned short* pa0 = A + (size_t)(bm + wr * 32 + l15) * FEATP + kb;
    const unsigned short* pa1 = pa0 + 16 * FEATP;
    const unsigned short* pb0 = Bw + (size_t)(bn + wc * 32 + l15) * FEATP + kb;
    const unsigned short* pb1 = pb0 + 16 * FEATP;

    f32x4 c00 = {0, 0, 0, 0}, c01 = {0, 0, 0, 0}, c10 = {0, 0, 0, 0}, c11 = {0, 0, 0, 0};

    bf16x8 a0  = __builtin_bit_cast(bf16x8, *(const uint4*)(pa0));
    bf16x8 a1  = __builtin_bit_cast(bf16x8, *(const uint4*)(pa1));
    bf16x8 bb0 = __builtin_bit_cast(bf16x8, *(const uint4*)(pb0));
    bf16x8 bb1 = __builtin_bit_cast(bf16x8, *(const uint4*)(pb1));
    #pragma unroll
    for (int kk = 0; kk < FEATP / 32 - 1; kk++) {
        bf16x8 na0  = __builtin_bit_cast(bf16x8, *(const uint4*)(pa0 + (kk + 1) * 32));
        bf16x8 na1  = __builtin_bit_cast(bf16x8, *(const uint4*)(pa1 + (kk + 1) * 32));
        bf16x8 nbb0 = __builtin_bit_cast(bf16x8, *(const uint4*)(pb0 + (kk + 1) * 32));
        bf16x8 nbb1 = __builtin_bit_cast(bf16x8, *(const uint4*)(pb1 + (kk + 1) * 32));
        c00 = __builtin_amdgcn_mfma_f32_16x16x32_bf16(a0, bb0, c00, 0, 0, 0);
        c01 = __builtin_amdgcn_mfma_f32_16x16x32_bf16(a0, bb1, c01, 0, 0, 0);
        c10 = __builtin_amdgcn_mfma_f32_16x16x32_bf16(a1, bb0, c10, 0, 0, 0);
        c11 = __builtin_amdgcn_mfma_f32_16x16x32_bf16(a1, bb1, c11, 0, 0, 0);
        a0 = na0; a1 = na1; bb0 = nbb0; bb1 = nbb1;
    }
    c00 = __builtin_amdgcn_mfma_f32_16x16x32_bf16(a0, bb0, c00, 0, 0, 0);
    c01 = __builtin_amdgcn_mfma_f32_16x16x32_bf16(a0, bb1, c01, 0, 0, 0);
    c10 = __builtin_amdgcn_mfma_f32_16x16x32_bf16(a1, bb0, c10, 0, 0, 0);
    c11 = __builtin_amdgcn_mfma_f32_16x16x32_bf16(a1, bb1, c11, 0, 0, 0);

    // C/D layout: col = lane&15, row = (lane>>4)*4 + reg   [learn_hip m89]
    int row0 = bm + wr * 32 + (lane >> 4) * 4;
    int col0 = bn + wc * 32 + l15;
    float bias0 = b1[col0];
    float bias1 = b1[col0 + 16];
    #pragma unroll
    for (int r = 0; r < 4; r++) {
        h[(size_t)(row0 + r) * H1 + col0]           = fmaxf(c00[r] + bias0, 0.f);
        h[(size_t)(row0 + r) * H1 + col0 + 16]      = fmaxf(c01[r] + bias1, 0.f);
        h[(size_t)(row0 + 16 + r) * H1 + col0]      = fmaxf(c10[r] + bias0, 0.f);
        h[(size_t)(row0 + 16 + r) * H1 + col0 + 16] = fmaxf(c11[r] + bias1, 0.f);
    }
}

// ---------------- K3: dueling head, one wave per batch row ----------------
__global__ __launch_bounds__(256) void k_out(const float* __restrict__ h,
                                             const float* __restrict__ wv,
                                             const float* __restrict__ bias,
                                             float* __restrict__ out, int nB)
{
    int wave = blockIdx.x * 4 + (threadIdx.x >> 6);
    int lane = threadIdx.x & 63;
    if (wave >= nB) return;
    const float4* hb4 = (const float4*)(h + (size_t)wave * H1 + lane * 8);
    float4 h0 = hb4[0], h1 = hb4[1];
    float acc[6];
    #pragma unroll
    for (int a = 0; a < 6; a++) {
        const float4* wp4 = (const float4*)(wv + a * H1 + lane * 8);
        float4 w0 = wp4[0], w1 = wp4[1];
        acc[a] = h0.x * w0.x + h0.y * w0.y + h0.z * w0.z + h0.w * w0.w
               + h1.x * w1.x + h1.y * w1.y + h1.z * w1.z + h1.w * w1.w;
    }
    #pragma unroll
    for (int a = 0; a < 6; a++) {
        #pragma unroll
        for (int off = 32; off > 0; off >>= 1) acc[a] += __shfl_xor(acc[a], off, 64);
    }
    float adv[5], ssum = 0.f;
    #pragma unroll
    for (int a = 0; a < 5; a++) { adv[a] = acc[a] + bias[a]; ssum += adv[a]; }
    float vv = acc[5] + bias[5];
    if (lane < 5) out[(size_t)wave * 5 + lane] = vv + adv[lane] - ssum * 0.2f;
}

extern "C" void kernel_launch(void* const* d_in, const int* in_sizes, int n_in,
                              void* d_out, int out_size, void* d_ws, size_t ws_size,
                              hipStream_t stream)
{
    const float* x      = (const float*)d_in[0];
    const float* Wg     = (const float*)d_in[1];
    const float* bg     = (const float*)d_in[2];
    const float* W1     = (const float*)d_in[3];
    const float* b1     = (const float*)d_in[4];
    const float* adv_uw = (const float*)d_in[5];
    const float* adv_sw = (const float*)d_in[6];
    const float* adv_ub = (const float*)d_in[7];
    const float* adv_sb = (const float*)d_in[8];
    const float* v_uw   = (const float*)d_in[9];
    const float* v_sw   = (const float*)d_in[10];
    const float* v_ub   = (const float*)d_in[11];
    const float* v_sb   = (const float*)d_in[12];
    const float* ei_a   = (const float*)d_in[13];
    const float* eo_a   = (const float*)d_in[14];
    const float* ei_v   = (const float*)d_in[15];
    const float* eo_v   = (const float*)d_in[16];

    int nB = in_sizes[0] / XROW;   // 4096

    char* ws = (char*)d_ws;
    unsigned short* w1bf   = (unsigned short*)ws;                         // 512*800*2
    unsigned short* featbf = (unsigned short*)(ws + 819200);              // nB*800*2
    float* h    = (float*)(ws + 819200 + (size_t)nB * FEATP * 2);         // nB*512*4
    float* wv   = (float*)((char*)h + (size_t)nB * H1 * 4);               // 6*512*4
    float* bias = wv + 6 * H1;                                            // 6*4
    float* out  = (float*)d_out;

    int nblk = (H1 * FEATP + 255) / 256 + 1;   // +1 block for noisy weights
    hipLaunchKernelGGL(k_prep, dim3(nblk), dim3(256), 0, stream, W1, w1bf,
                       adv_uw, adv_sw, adv_ub, adv_sb, v_uw, v_sw, v_ub, v_sb,
                       ei_a, eo_a, ei_v, eo_v, wv, bias, nblk);
    hipLaunchKernelGGL(k_feat, dim3(nB), dim3(128), 0, stream, x, Wg, bg, featbf);
    hipLaunchKernelGGL(k_gemm, dim3((nB / 64) * (H1 / 64)), dim3(256), 0, stream,
                       featbf, w1bf, b1, h, nB);
    hipLaunchKernelGGL(k_out, dim3((nB + 3) / 4), dim3(256), 0, stream, h, wv, bias, out, nB);
}

// Round 5
// 148.158 us; speedup vs baseline: 1.1981x; 1.0028x over previous
//
#include <hip/hip_runtime.h>
#include <hip/hip_bf16.h>
#include <stdint.h>

#define KNN 8
#define S_ 5
#define D_ 5
#define NDE 4
#define NDC 12
#define NDCP 13
#define NDD 16
#define NPOS 80
#define ACT 5
#define PERK 172
#define XROW 1376
#define FEAT 784
#define FEATP 832
#define KSTEPS 26
#define H1 512

typedef __bf16 bf16x8 __attribute__((ext_vector_type(8)));
typedef float f32x4 __attribute__((ext_vector_type(4)));

static __device__ __forceinline__ unsigned short f2bf(float f) {
    unsigned int u = __builtin_bit_cast(unsigned int, f);
    u += 0x7fff + ((u >> 16) & 1);   // round-to-nearest-even
    return (unsigned short)(u >> 16);
}
static __device__ __forceinline__ float fsgnsqrt(float t) {
    return copysignf(sqrtf(fabsf(t)), t);
}

// ---------------- K0: W1 -> bf16 (K-pad 784->832)  +  noisy weights (last block) ----------------
__global__ __launch_bounds__(256) void k_prep(const float* __restrict__ W1,
                                              unsigned short* __restrict__ w1bf,
                                              const float* __restrict__ adv_uw,
                                              const float* __restrict__ adv_sw,
                                              const float* __restrict__ adv_ub,
                                              const float* __restrict__ adv_sb,
                                              const float* __restrict__ v_uw,
                                              const float* __restrict__ v_sw,
                                              const float* __restrict__ v_ub,
                                              const float* __restrict__ v_sb,
                                              const float* __restrict__ ei_a,
                                              const float* __restrict__ eo_a,
                                              const float* __restrict__ ei_v,
                                              const float* __restrict__ eo_v,
                                              float* __restrict__ wv,
                                              float* __restrict__ bias,
                                              int nblk)
{
    if ((int)blockIdx.x == nblk - 1) {
        int tid = threadIdx.x;
        for (int n = tid; n < H1; n += 256) {
            float fia = fsgnsqrt(ei_a[n]);
            float fiv = fsgnsqrt(ei_v[n]);
            #pragma unroll
            for (int a = 0; a < ACT; a++)
                wv[a * H1 + n] = adv_uw[a * H1 + n] + adv_sw[a * H1 + n] * fsgnsqrt(eo_a[a]) * fia;
            wv[5 * H1 + n] = v_uw[n] + v_sw[n] * fsgnsqrt(eo_v[0]) * fiv;
        }
        if (tid < ACT) bias[tid] = adv_ub[tid] + adv_sb[tid] * fsgnsqrt(eo_a[tid]);
        if (tid == ACT) bias[5] = v_ub[0] + v_sb[0] * fsgnsqrt(eo_v[0]);
        return;
    }
    int idx = blockIdx.x * 256 + threadIdx.x;
    if (idx >= H1 * FEATP) return;
    int n = idx / FEATP, k = idx - n * FEATP;
    float v = (k < FEAT) ? W1[n * FEAT + k] : 0.f;
    w1bf[idx] = f2bf(v);
}

// ---------------- K1: GNN + gather -> feat (bf16, padded to 832) ----------------
__global__ __launch_bounds__(128) void k_feat(const float* __restrict__ x,
                                              const float* __restrict__ Wg,
                                              const float* __restrict__ bg,
                                              unsigned short* __restrict__ featbf)
{
    __shared__ float xrow[XROW];
    __shared__ float sWg[NDC * NDC];
    __shared__ float sbg[NDC];
    __shared__ int   snd[NPOS];
    __shared__ int   sfirst[NPOS];
    __shared__ int   smfirst[NPOS];
    __shared__ float scw[NPOS];          // cnt * dis
    __shared__ float sdis[NPOS];
    __shared__ float sM[NPOS * NDCP];
    __shared__ float sH[NPOS * NDCP];
    __shared__ unsigned int tFirst[1024];  // node-id -> first occurrence idx (127 = none)
    __shared__ unsigned int tCnt[1024];    // node-id -> multiplicity

    const int b = blockIdx.x;
    const int tid = threadIdx.x;
    const float4* xp4 = (const float4*)(x + (size_t)b * XROW);
    float4* xr4 = (float4*)xrow;
    #pragma unroll
    for (int i = tid; i < XROW / 4; i += 128) xr4[i] = xp4[i];
    for (int i = tid; i < NDC * NDC; i += 128) sWg[i] = Wg[i];
    if (tid < NDC) sbg[tid] = bg[tid];
    #pragma unroll
    for (int i = tid; i < 1024; i += 128) { tFirst[i] = 127u; tCnt[i] = 0u; }
    __syncthreads();

    if (tid < NPOS) {
        int k = tid / 10, m = tid % 10;
        int nd = (int)xrow[k * PERK + 160 + m];
        snd[tid] = nd;
        atomicMin(&tFirst[nd], (unsigned)tid);
        atomicAdd(&tCnt[nd], 1u);
    }
    __syncthreads();

    int s0 = 127, s1 = 127, s2 = 127, s3 = 127;
    if (tid < NPOS) {
        const int i = tid;
        const int ndi = snd[i];
        const int kbase = (i / 10) * 10;
        int r = ndi >> 5, c = ndi & 31;
        int nb0 = (((r + 31) & 31) << 5) | c;
        int nb1 = (((r + 1) & 31) << 5) | c;
        int nb2 = (r << 5) | ((c + 31) & 31);
        int nb3 = (r << 5) | ((c + 1) & 31);
        int f = (int)tFirst[ndi];
        int cnt = (int)tCnt[ndi];
        s0 = (int)tFirst[nb0]; s1 = (int)tFirst[nb1];
        s2 = (int)tFirst[nb2]; s3 = (int)tFirst[nb3];
        int adjd = (int)(tCnt[nb0] + tCnt[nb1] + tCnt[nb2] + tCnt[nb3]);
        int mf = 127;
        #pragma unroll
        for (int jj = 9; jj >= 0; jj--) {
            if (snd[kbase + jj] == ndi) mf = kbase + jj;
        }
        sfirst[i] = f;
        smfirst[i] = mf;
        float dis = rsqrtf(1.0f + ((f == i) ? (float)adjd : 0.0f));
        sdis[i] = dis;
        scw[i] = (float)cnt * dis;
        // M = all_info @ Wg, one row per thread
        int off = (i / 10) * PERK + (i % 10) * NDD;
        float ai[NDC];
        #pragma unroll
        for (int c2 = 0; c2 < NDC; c2++) ai[c2] = xrow[off + NDE + c2];
        #pragma unroll
        for (int d = 0; d < NDC; d++) {
            float s = 0.f;
            #pragma unroll
            for (int c2 = 0; c2 < NDC; c2++) s += ai[c2] * sWg[c2 * NDC + d];
            sM[i * NDCP + d] = s;
        }
    }
    __syncthreads();

    // H[t] = relu( d_t^2*M[t] + is_first[t]*d_t*sum_{nbr first sX} cnt_sX*d_sX*M[sX] + bg )
    if (tid < NPOS) {
        const int t = tid;
        float dt = sdis[t];
        float d2 = dt * dt;
        float acc[NDC];
        #pragma unroll
        for (int d = 0; d < NDC; d++) acc[d] = d2 * sM[t * NDCP + d];
        if (sfirst[t] == t) {
            #pragma unroll
            for (int X = 0; X < 4; X++) {
                int sX = (X == 0) ? s0 : (X == 1) ? s1 : (X == 2) ? s2 : s3;
                if (sX < NPOS) {
                    float w = scw[sX] * dt;
                    #pragma unroll
                    for (int d = 0; d < NDC; d++) acc[d] += w * sM[sX * NDCP + d];
                }
            }
        }
        #pragma unroll
        for (int d = 0; d < NDC; d++) sH[t * NDCP + d] = fmaxf(acc[d] + sbg[d], 0.f);
    }
    __syncthreads();

    // gather: per k: [6x12 gnn][2 els][6x4 each]; pad 784->832 with zeros
    unsigned short* fout = featbf + (size_t)b * FEATP;
    for (int idx = tid; idx < FEATP; idx += 128) {
        float val = 0.f;
        if (idx < FEAT) {
            int k = idx / 98, rr = idx % 98;
            if (rr < 72) {
                int t = rr / 12, d = rr % 12;
                val = sH[sfirst[k * 10 + t] * NDCP + d];
            } else if (rr < 74) {
                val = xrow[k * PERK + 170 + (rr - 72)];
            } else {
                int q = rr - 74;
                int t = q >> 2, e = q & 3;
                int m = smfirst[k * 10 + t] - k * 10;
                val = xrow[k * PERK + m * NDD + e];
            }
        }
        fout[idx] = f2bf(val);
    }
}

// ---------------- K2: h = relu(feat @ W1^T + b1), bf16 MFMA, 2-deep prefetch ----------------
#define LDF(p, kk) __builtin_bit_cast(bf16x8, *(const uint4*)((p) + (kk) * 32))

__global__ __launch_bounds__(256) void k_gemm(const unsigned short* __restrict__ A,
                                              const unsigned short* __restrict__ Bw,
                                              const float* __restrict__ b1,
                                              float* __restrict__ h, int nB)
{
    int tid = threadIdx.x;
    int lane = tid & 63;
    int w = tid >> 6;
    // bijective XCD chunking: nwg = (nB/64)*8, divisible by 8
    int nwg = (nB >> 6) * 8;
    int cpx = nwg >> 3;
    int orig = blockIdx.x;
    int wg = (orig & 7) * cpx + (orig >> 3);
    int bn = (wg & 7) * 64;            // bn-major: 8 consecutive wg share one A-tile
    int bm = (wg >> 3) * 64;
    int wr = w >> 1, wc = w & 1;
    int l15 = lane & 15;
    int kb = (lane >> 4) * 8;

    const unsigned short* pa0 = A + (size_t)(bm + wr * 32 + l15) * FEATP + kb;
    const unsigned short* pa1 = pa0 + 16 * FEATP;
    const unsigned short* pb0 = Bw + (size_t)(bn + wc * 32 + l15) * FEATP + kb;
    const unsigned short* pb1 = pb0 + 16 * FEATP;

    f32x4 c00 = {0, 0, 0, 0}, c01 = {0, 0, 0, 0}, c10 = {0, 0, 0, 0}, c11 = {0, 0, 0, 0};

    bf16x8 a0A = LDF(pa0, 0), a1A = LDF(pa1, 0), b0A = LDF(pb0, 0), b1A = LDF(pb1, 0);
    bf16x8 a0B = LDF(pa0, 1), a1B = LDF(pa1, 1), b0B = LDF(pb0, 1), b1B = LDF(pb1, 1);

    #pragma unroll
    for (int kk = 0; kk < KSTEPS; kk += 2) {
        bf16x8 na0A, na1A, nb0A, nb1A, na0B, na1B, nb0B, nb1B;
        if (kk + 2 < KSTEPS) {
            na0A = LDF(pa0, kk + 2); na1A = LDF(pa1, kk + 2);
            nb0A = LDF(pb0, kk + 2); nb1A = LDF(pb1, kk + 2);
            na0B = LDF(pa0, kk + 3); na1B = LDF(pa1, kk + 3);
            nb0B = LDF(pb0, kk + 3); nb1B = LDF(pb1, kk + 3);
        }
        c00 = __builtin_amdgcn_mfma_f32_16x16x32_bf16(a0A, b0A, c00, 0, 0, 0);
        c01 = __builtin_amdgcn_mfma_f32_16x16x32_bf16(a0A, b1A, c01, 0, 0, 0);
        c10 = __builtin_amdgcn_mfma_f32_16x16x32_bf16(a1A, b0A, c10, 0, 0, 0);
        c11 = __builtin_amdgcn_mfma_f32_16x16x32_bf16(a1A, b1A, c11, 0, 0, 0);
        c00 = __builtin_amdgcn_mfma_f32_16x16x32_bf16(a0B, b0B, c00, 0, 0, 0);
        c01 = __builtin_amdgcn_mfma_f32_16x16x32_bf16(a0B, b1B, c01, 0, 0, 0);
        c10 = __builtin_amdgcn_mfma_f32_16x16x32_bf16(a1B, b0B, c10, 0, 0, 0);
        c11 = __builtin_amdgcn_mfma_f32_16x16x32_bf16(a1B, b1B, c11, 0, 0, 0);
        if (kk + 2 < KSTEPS) {
            a0A = na0A; a1A = na1A; b0A = nb0A; b1A = nb1A;
            a0B = na0B; a1B = na1B; b0B = nb0B; b1B = nb1B;
        }
    }

    // C/D layout: col = lane&15, row = (lane>>4)*4 + reg   [learn_hip m89]
    int row0 = bm + wr * 32 + (lane >> 4) * 4;
    int col0 = bn + wc * 32 + l15;
    float bias0 = b1[col0];
    float bias1 = b1[col0 + 16];
    #pragma unroll
    for (int r = 0; r < 4; r++) {
        h[(size_t)(row0 + r) * H1 + col0]           = fmaxf(c00[r] + bias0, 0.f);
        h[(size_t)(row0 + r) * H1 + col0 + 16]      = fmaxf(c01[r] + bias1, 0.f);
        h[(size_t)(row0 + 16 + r) * H1 + col0]      = fmaxf(c10[r] + bias0, 0.f);
        h[(size_t)(row0 + 16 + r) * H1 + col0 + 16] = fmaxf(c11[r] + bias1, 0.f);
    }
}

// ---------------- K3: dueling head, one wave per batch row ----------------
__global__ __launch_bounds__(256) void k_out(const float* __restrict__ h,
                                             const float* __restrict__ wv,
                                             const float* __restrict__ bias,
                                             float* __restrict__ out, int nB)
{
    int wave = blockIdx.x * 4 + (threadIdx.x >> 6);
    int lane = threadIdx.x & 63;
    if (wave >= nB) return;
    const float4* hb4 = (const float4*)(h + (size_t)wave * H1 + lane * 8);
    float4 h0 = hb4[0], h1 = hb4[1];
    float acc[6];
    #pragma unroll
    for (int a = 0; a < 6; a++) {
        const float4* wp4 = (const float4*)(wv + a * H1 + lane * 8);
        float4 w0 = wp4[0], w1 = wp4[1];
        acc[a] = h0.x * w0.x + h0.y * w0.y + h0.z * w0.z + h0.w * w0.w
               + h1.x * w1.x + h1.y * w1.y + h1.z * w1.z + h1.w * w1.w;
    }
    #pragma unroll
    for (int a = 0; a < 6; a++) {
        #pragma unroll
        for (int off = 32; off > 0; off >>= 1) acc[a] += __shfl_xor(acc[a], off, 64);
    }
    float adv[5], ssum = 0.f;
    #pragma unroll
    for (int a = 0; a < 5; a++) { adv[a] = acc[a] + bias[a]; ssum += adv[a]; }
    float vv = acc[5] + bias[5];
    if (lane < 5) out[(size_t)wave * 5 + lane] = vv + adv[lane] - ssum * 0.2f;
}

extern "C" void kernel_launch(void* const* d_in, const int* in_sizes, int n_in,
                              void* d_out, int out_size, void* d_ws, size_t ws_size,
                              hipStream_t stream)
{
    const float* x      = (const float*)d_in[0];
    const float* Wg     = (const float*)d_in[1];
    const float* bg     = (const float*)d_in[2];
    const float* W1     = (const float*)d_in[3];
    const float* b1     = (const float*)d_in[4];
    const float* adv_uw = (const float*)d_in[5];
    const float* adv_sw = (const float*)d_in[6];
    const float* adv_ub = (const float*)d_in[7];
    const float* adv_sb = (const float*)d_in[8];
    const float* v_uw   = (const float*)d_in[9];
    const float* v_sw   = (const float*)d_in[10];
    const float* v_ub   = (const float*)d_in[11];
    const float* v_sb   = (const float*)d_in[12];
    const float* ei_a   = (const float*)d_in[13];
    const float* eo_a   = (const float*)d_in[14];
    const float* ei_v   = (const float*)d_in[15];
    const float* eo_v   = (const float*)d_in[16];

    int nB = in_sizes[0] / XROW;   // 4096

    char* ws = (char*)d_ws;
    size_t off_feat = (size_t)H1 * FEATP * 2;                       // 851968
    unsigned short* w1bf   = (unsigned short*)ws;
    unsigned short* featbf = (unsigned short*)(ws + off_feat);
    float* h    = (float*)(ws + off_feat + (size_t)nB * FEATP * 2);
    float* wv   = (float*)((char*)h + (size_t)nB * H1 * 4);
    float* bias = wv + 6 * H1;
    float* out  = (float*)d_out;

    int nblk = (H1 * FEATP + 255) / 256 + 1;   // +1 block for noisy weights
    hipLaunchKernelGGL(k_prep, dim3(nblk), dim3(256), 0, stream, W1, w1bf,
                       adv_uw, adv_sw, adv_ub, adv_sb, v_uw, v_sw, v_ub, v_sb,
                       ei_a, eo_a, ei_v, eo_v, wv, bias, nblk);
    hipLaunchKernelGGL(k_feat, dim3(nB), dim3(128), 0, stream, x, Wg, bg, featbf);
    hipLaunchKernelGGL(k_gemm, dim3((nB / 64) * (H1 / 64)), dim3(256), 0, stream,
                       featbf, w1bf, b1, h, nB);
    hipLaunchKernelGGL(k_out, dim3((nB + 3) / 4), dim3(256), 0, stream, h, wv, bias, out, nB);
}

// Round 6
// 137.462 us; speedup vs baseline: 1.2913x; 1.0778x over previous
//
#include <hip/hip_runtime.h>
#include <hip/hip_bf16.h>
#include <stdint.h>

#define KNN 8
#define S_ 5
#define D_ 5
#define NDE 4
#define NDC 12
#define NDCP 13
#define NDD 16
#define NPOS 80
#define ACT 5
#define PERK 172
#define XROW 1376
#define FEAT 784
#define FEATP 800
#define KSTEPS 25
#define H1 512

typedef __bf16 bf16x8 __attribute__((ext_vector_type(8)));
typedef float f32x4 __attribute__((ext_vector_type(4)));

static __device__ __forceinline__ unsigned short f2bf(float f) {
    unsigned int u = __builtin_bit_cast(unsigned int, f);
    u += 0x7fff + ((u >> 16) & 1);   // round-to-nearest-even
    return (unsigned short)(u >> 16);
}
static __device__ __forceinline__ float fsgnsqrt(float t) {
    return copysignf(sqrtf(fabsf(t)), t);
}

// ---------------- K1 (fused): feat blocks [0,nB) | W1->bf16 blocks [nB,nB+800) | noisy block ----------------
__global__ __launch_bounds__(128) void k_pre(const float* __restrict__ x,
                                             const float* __restrict__ Wg,
                                             const float* __restrict__ bg,
                                             unsigned short* __restrict__ featbf,
                                             const float* __restrict__ W1,
                                             unsigned short* __restrict__ w1bf,
                                             const float* __restrict__ adv_uw,
                                             const float* __restrict__ adv_sw,
                                             const float* __restrict__ adv_ub,
                                             const float* __restrict__ adv_sb,
                                             const float* __restrict__ v_uw,
                                             const float* __restrict__ v_sw,
                                             const float* __restrict__ v_ub,
                                             const float* __restrict__ v_sb,
                                             const float* __restrict__ ei_a,
                                             const float* __restrict__ eo_a,
                                             const float* __restrict__ ei_v,
                                             const float* __restrict__ eo_v,
                                             float* __restrict__ wv,
                                             float* __restrict__ bias,
                                             int nB)
{
    const int bid = blockIdx.x;
    const int tid = threadIdx.x;

    if (bid >= nB) {
        int pb = bid - nB;
        if (pb < 800) {
            // W1 f32 -> bf16, K-pad 784->800; 4 elements per thread
            int idx0 = (pb * 128 + tid) * 4;
            int n = idx0 / FEATP, k = idx0 - n * FEATP;
            ushort4 o;
            if (k < FEAT) {   // groups never straddle the 784 boundary (784%4==0)
                float4 v = *(const float4*)(W1 + (size_t)n * FEAT + k);
                o.x = f2bf(v.x); o.y = f2bf(v.y); o.z = f2bf(v.z); o.w = f2bf(v.w);
            } else {
                o.x = o.y = o.z = o.w = 0;
            }
            *(ushort4*)(w1bf + idx0) = o;
        } else {
            // noisy-net effective weights
            for (int n = tid; n < H1; n += 128) {
                float fia = fsgnsqrt(ei_a[n]);
                float fiv = fsgnsqrt(ei_v[n]);
                #pragma unroll
                for (int a = 0; a < ACT; a++)
                    wv[a * H1 + n] = adv_uw[a * H1 + n] + adv_sw[a * H1 + n] * fsgnsqrt(eo_a[a]) * fia;
                wv[5 * H1 + n] = v_uw[n] + v_sw[n] * fsgnsqrt(eo_v[0]) * fiv;
            }
            if (tid < ACT) bias[tid] = adv_ub[tid] + adv_sb[tid] * fsgnsqrt(eo_a[tid]);
            if (tid == ACT) bias[5] = v_ub[0] + v_sb[0] * fsgnsqrt(eo_v[0]);
        }
        return;
    }

    // ---- feat role ----
    __shared__ float xrow[XROW];
    __shared__ float sWg[NDC * NDC];
    __shared__ float sbg[NDC];
    __shared__ int   snd[NPOS];
    __shared__ int   sfirst[NPOS];
    __shared__ int   smfirst[NPOS];
    __shared__ float scw[NPOS];           // cnt * dis (valid at first indices)
    __shared__ float sdis[NPOS];
    __shared__ int   sNB[NPOS][4];        // first idx of each grid-neighbor value (127=absent)
    __shared__ float sM[NPOS * NDCP];
    // tbl (u32[1024], live until c1) and sH (f32[1040], live from (d)) share storage:
    __shared__ __align__(16) char uShared[NPOS * NDCP * 4];
    unsigned int* tbl = (unsigned int*)uShared;
    float* sH = (float*)uShared;

    const float4* xp4 = (const float4*)(x + (size_t)bid * XROW);
    float4* xr4 = (float4*)xrow;
    #pragma unroll
    for (int i = tid; i < XROW / 4; i += 128) xr4[i] = xp4[i];
    for (int i = tid; i < NDC * NDC; i += 128) sWg[i] = Wg[i];
    if (tid < NDC) sbg[tid] = bg[tid];
    #pragma unroll
    for (int i = tid; i < 1024; i += 128) tbl[i] = 127u;
    __syncthreads();

    if (tid < NPOS) {
        int k = tid / 10, m = tid % 10;
        int nd = (int)xrow[k * PERK + 160 + m];
        snd[tid] = nd;
        atomicMin(&tbl[nd], (unsigned)tid);   // cnt bits are 0 in this phase -> pure min on first
    }
    __syncthreads();
    if (tid < NPOS) atomicAdd(&tbl[snd[tid]], 256u);   // cnt in bits 8+
    __syncthreads();

    // c1: per-node scalars (80 threads)
    if (tid < NPOS) {
        const int i = tid;
        const int ndi = snd[i];
        const int kbase = (i / 10) * 10;
        int r = ndi >> 5, c = ndi & 31;
        int nb0 = (((r + 31) & 31) << 5) | c;
        int nb1 = (((r + 1) & 31) << 5) | c;
        int nb2 = (r << 5) | ((c + 31) & 31);
        int nb3 = (r << 5) | ((c + 1) & 31);
        unsigned v = tbl[ndi];
        int f = (int)(v & 0xFFu);
        int cnt = (int)(v >> 8);
        unsigned v0 = tbl[nb0], v1 = tbl[nb1], v2 = tbl[nb2], v3 = tbl[nb3];
        sNB[i][0] = (int)(v0 & 0xFFu);
        sNB[i][1] = (int)(v1 & 0xFFu);
        sNB[i][2] = (int)(v2 & 0xFFu);
        sNB[i][3] = (int)(v3 & 0xFFu);
        int adjd = (int)((v0 >> 8) + (v1 >> 8) + (v2 >> 8) + (v3 >> 8));
        int mf = 127;
        #pragma unroll
        for (int jj = 9; jj >= 0; jj--) {
            if (snd[kbase + jj] == ndi) mf = kbase + jj;
        }
        sfirst[i] = f;
        smfirst[i] = mf;
        float dis = rsqrtf(1.0f + ((f == i) ? (float)adjd : 0.0f));
        sdis[i] = dis;
        scw[i] = (float)cnt * dis;
    }
    // c2: M = all_info @ Wg, 960 (i,d) items over all 128 threads
    for (int p = tid; p < NPOS * NDC; p += 128) {
        int i = p / NDC, d = p - i * NDC;
        int off = (i / 10) * PERK + (i % 10) * NDD + NDE;
        float s = 0.f;
        #pragma unroll
        for (int c2 = 0; c2 < NDC; c2++) s += xrow[off + c2] * sWg[c2 * NDC + d];
        sM[i * NDCP + d] = s;
    }
    __syncthreads();   // tbl dead beyond this point; sH may now be written

    // d: H[t,d] = relu( dis_t^2*M[t,d] + is_first[t]*dis_t*sum_X scw[sX]*M[sX,d] + bg[d] )
    for (int p = tid; p < NPOS * NDC; p += 128) {
        int t = p / NDC, d = p - t * NDC;
        float dt = sdis[t];
        float a = dt * dt * sM[t * NDCP + d];
        if (sfirst[t] == t) {
            #pragma unroll
            for (int X = 0; X < 4; X++) {
                int sX = sNB[t][X];
                if (sX < NPOS) a += scw[sX] * dt * sM[sX * NDCP + d];
            }
        }
        sH[t * NDCP + d] = fmaxf(a + sbg[d], 0.f);
    }
    __syncthreads();

    // gather: per k: [6x12 gnn][2 els][6x4 each]; pad 784->800 with zeros
    unsigned short* fout = featbf + (size_t)bid * FEATP;
    for (int idx = tid; idx < FEATP; idx += 128) {
        float val = 0.f;
        if (idx < FEAT) {
            int k = idx / 98, rr = idx % 98;
            if (rr < 72) {
                int t = rr / 12, d = rr % 12;
                val = sH[sfirst[k * 10 + t] * NDCP + d];
            } else if (rr < 74) {
                val = xrow[k * PERK + 170 + (rr - 72)];
            } else {
                int q = rr - 74;
                int t = q >> 2, e = q & 3;
                int m = smfirst[k * 10 + t] - k * 10;
                val = xrow[k * PERK + m * NDD + e];
            }
        }
        fout[idx] = f2bf(val);
    }
}

// ---------------- K2: h = relu(feat @ W1^T + b1), bf16 MFMA, 1-deep prefetch ----------------
#define LDF(p, kk) __builtin_bit_cast(bf16x8, *(const uint4*)((p) + (kk) * 32))

__global__ __launch_bounds__(256) void k_gemm(const unsigned short* __restrict__ A,
                                              const unsigned short* __restrict__ Bw,
                                              const float* __restrict__ b1,
                                              float* __restrict__ h, int nB)
{
    int tid = threadIdx.x;
    int lane = tid & 63;
    int w = tid >> 6;
    // bijective XCD chunking: nwg = (nB/64)*8, divisible by 8
    int nwg = (nB >> 6) * 8;
    int cpx = nwg >> 3;
    int orig = blockIdx.x;
    int wg = (orig & 7) * cpx + (orig >> 3);
    int bn = (wg & 7) * 64;            // bn-major: 8 consecutive wg share one A-tile
    int bm = (wg >> 3) * 64;
    int wr = w >> 1, wc = w & 1;
    int l15 = lane & 15;
    int kb = (lane >> 4) * 8;

    const unsigned short* pa0 = A + (size_t)(bm + wr * 32 + l15) * FEATP + kb;
    const unsigned short* pa1 = pa0 + 16 * FEATP;
    const unsigned short* pb0 = Bw + (size_t)(bn + wc * 32 + l15) * FEATP + kb;
    const unsigned short* pb1 = pb0 + 16 * FEATP;

    f32x4 c00 = {0, 0, 0, 0}, c01 = {0, 0, 0, 0}, c10 = {0, 0, 0, 0}, c11 = {0, 0, 0, 0};

    bf16x8 a0  = LDF(pa0, 0);
    bf16x8 a1  = LDF(pa1, 0);
    bf16x8 bb0 = LDF(pb0, 0);
    bf16x8 bb1 = LDF(pb1, 0);
    #pragma unroll
    for (int kk = 0; kk < KSTEPS - 1; kk++) {
        bf16x8 na0  = LDF(pa0, kk + 1);
        bf16x8 na1  = LDF(pa1, kk + 1);
        bf16x8 nbb0 = LDF(pb0, kk + 1);
        bf16x8 nbb1 = LDF(pb1, kk + 1);
        c00 = __builtin_amdgcn_mfma_f32_16x16x32_bf16(a0, bb0, c00, 0, 0, 0);
        c01 = __builtin_amdgcn_mfma_f32_16x16x32_bf16(a0, bb1, c01, 0, 0, 0);
        c10 = __builtin_amdgcn_mfma_f32_16x16x32_bf16(a1, bb0, c10, 0, 0, 0);
        c11 = __builtin_amdgcn_mfma_f32_16x16x32_bf16(a1, bb1, c11, 0, 0, 0);
        a0 = na0; a1 = na1; bb0 = nbb0; bb1 = nbb1;
    }
    c00 = __builtin_amdgcn_mfma_f32_16x16x32_bf16(a0, bb0, c00, 0, 0, 0);
    c01 = __builtin_amdgcn_mfma_f32_16x16x32_bf16(a0, bb1, c01, 0, 0, 0);
    c10 = __builtin_amdgcn_mfma_f32_16x16x32_bf16(a1, bb0, c10, 0, 0, 0);
    c11 = __builtin_amdgcn_mfma_f32_16x16x32_bf16(a1, bb1, c11, 0, 0, 0);

    // C/D layout: col = lane&15, row = (lane>>4)*4 + reg   [learn_hip m89]
    int row0 = bm + wr * 32 + (lane >> 4) * 4;
    int col0 = bn + wc * 32 + l15;
    float bias0 = b1[col0];
    float bias1 = b1[col0 + 16];
    #pragma unroll
    for (int r = 0; r < 4; r++) {
        h[(size_t)(row0 + r) * H1 + col0]           = fmaxf(c00[r] + bias0, 0.f);
        h[(size_t)(row0 + r) * H1 + col0 + 16]      = fmaxf(c01[r] + bias1, 0.f);
        h[(size_t)(row0 + 16 + r) * H1 + col0]      = fmaxf(c10[r] + bias0, 0.f);
        h[(size_t)(row0 + 16 + r) * H1 + col0 + 16] = fmaxf(c11[r] + bias1, 0.f);
    }
}

// ---------------- K3: dueling head, one wave per batch row ----------------
__global__ __launch_bounds__(256) void k_out(const float* __restrict__ h,
                                             const float* __restrict__ wv,
                                             const float* __restrict__ bias,
                                             float* __restrict__ out, int nB)
{
    int wave = blockIdx.x * 4 + (threadIdx.x >> 6);
    int lane = threadIdx.x & 63;
    if (wave >= nB) return;
    const float4* hb4 = (const float4*)(h + (size_t)wave * H1 + lane * 8);
    float4 h0 = hb4[0], h1 = hb4[1];
    float acc[6];
    #pragma unroll
    for (int a = 0; a < 6; a++) {
        const float4* wp4 = (const float4*)(wv + a * H1 + lane * 8);
        float4 w0 = wp4[0], w1 = wp4[1];
        acc[a] = h0.x * w0.x + h0.y * w0.y + h0.z * w0.z + h0.w * w0.w
               + h1.x * w1.x + h1.y * w1.y + h1.z * w1.z + h1.w * w1.w;
    }
    #pragma unroll
    for (int a = 0; a < 6; a++) {
        #pragma unroll
        for (int off = 32; off > 0; off >>= 1) acc[a] += __shfl_xor(acc[a], off, 64);
    }
    float adv[5], ssum = 0.f;
    #pragma unroll
    for (int a = 0; a < 5; a++) { adv[a] = acc[a] + bias[a]; ssum += adv[a]; }
    float vv = acc[5] + bias[5];
    if (lane < 5) out[(size_t)wave * 5 + lane] = vv + adv[lane] - ssum * 0.2f;
}

extern "C" void kernel_launch(void* const* d_in, const int* in_sizes, int n_in,
                              void* d_out, int out_size, void* d_ws, size_t ws_size,
                              hipStream_t stream)
{
    const float* x      = (const float*)d_in[0];
    const float* Wg     = (const float*)d_in[1];
    const float* bg     = (const float*)d_in[2];
    const float* W1     = (const float*)d_in[3];
    const float* b1     = (const float*)d_in[4];
    const float* adv_uw = (const float*)d_in[5];
    const float* adv_sw = (const float*)d_in[6];
    const float* adv_ub = (const float*)d_in[7];
    const float* adv_sb = (const float*)d_in[8];
    const float* v_uw   = (const float*)d_in[9];
    const float* v_sw   = (const float*)d_in[10];
    const float* v_ub   = (const float*)d_in[11];
    const float* v_sb   = (const float*)d_in[12];
    const float* ei_a   = (const float*)d_in[13];
    const float* eo_a   = (const float*)d_in[14];
    const float* ei_v   = (const float*)d_in[15];
    const float* eo_v   = (const float*)d_in[16];

    int nB = in_sizes[0] / XROW;   // 4096

    char* ws = (char*)d_ws;
    size_t off_feat = (size_t)H1 * FEATP * 2;                       // 819200
    unsigned short* w1bf   = (unsigned short*)ws;
    unsigned short* featbf = (unsigned short*)(ws + off_feat);
    float* h    = (float*)(ws + off_feat + (size_t)nB * FEATP * 2);
    float* wv   = (float*)((char*)h + (size_t)nB * H1 * 4);
    float* bias = wv + 6 * H1;
    float* out  = (float*)d_out;

    // fused: nB feat blocks + 800 W1-convert blocks + 1 noisy block
    hipLaunchKernelGGL(k_pre, dim3(nB + 801), dim3(128), 0, stream,
                       x, Wg, bg, featbf, W1, w1bf,
                       adv_uw, adv_sw, adv_ub, adv_sb, v_uw, v_sw, v_ub, v_sb,
                       ei_a, eo_a, ei_v, eo_v, wv, bias, nB);
    hipLaunchKernelGGL(k_gemm, dim3((nB / 64) * (H1 / 64)), dim3(256), 0, stream,
                       featbf, w1bf, b1, h, nB);
    hipLaunchKernelGGL(k_out, dim3((nB + 3) / 4), dim3(256), 0, stream, h, wv, bias, out, nB);
}